// Round 1
// baseline (299.111 us; speedup 1.0000x reference)
//
#include <hip/hip_runtime.h>
#include <cstdint>

// Problem constants
#define LSEQ 1024
#define BATCH 16
#define NIN 1024
#define NOUT 512
#define KGATE 5
#define NCOL (NOUT * KGATE)           // 2560
#define MTOT (LSEQ * BATCH)           // 16384
#define CHAINS (BATCH * NOUT)         // 8192
#define OUT_GCS (LSEQ * BATCH * NOUT) // 8388608
#define SEG 32                        // segments
#define SLEN 32                       // steps per segment
#define PLANE ((size_t)MTOT * NOUT)   // elements per gate plane (8M)
#define SMP ((size_t)SEG * CHAINS)    // elements per segmap plane (256K)

// GEMM geometry (8-phase 256x256 template, m201 structure)
#define BM 256
#define BN 256
#define BK 64
#define NTILES (NIN / BK)             // 16
#define NOBJ (4 * NTILES)             // 64 staged half-tiles total

typedef _Float16 f16x8 __attribute__((ext_vector_type(8)));
typedef _Float16 f16x4 __attribute__((ext_vector_type(4)));
typedef float f32x4 __attribute__((ext_vector_type(4)));

__device__ __forceinline__ void async16(const void* g, void* l) {
    __builtin_amdgcn_global_load_lds(
        (const __attribute__((address_space(1))) void*)(uintptr_t)g,
        (__attribute__((address_space(3))) void*)(uintptr_t)l,
        16, 0, 0);
}

__device__ __forceinline__ float fsigmoid(float x) {
    return 1.0f / (1.0f + __expf(-x));
}

// ---------------- Kernel 1: convert x fp32 -> f16 (8 elems/thread) ----------------
__global__ void convert_x_k(const float* __restrict__ x, _Float16* __restrict__ xb, int n8) {
    int i = blockIdx.x * blockDim.x + threadIdx.x;
    if (i < n8) {
        float4 a = ((const float4*)x)[2 * i];
        float4 b = ((const float4*)x)[2 * i + 1];
        f16x8 h;
        h[0] = (_Float16)a.x; h[1] = (_Float16)a.y; h[2] = (_Float16)a.z; h[3] = (_Float16)a.w;
        h[4] = (_Float16)b.x; h[5] = (_Float16)b.y; h[6] = (_Float16)b.z; h[7] = (_Float16)b.w;
        ((f16x8*)xb)[i] = h;
    }
}

// ---------------- Kernel 2: transpose+convert+PERMUTE weight ----------------
// w [1024][2560] f32 -> wT [2560][1024] f16; orig col c=n*5+g -> row' = g*512+n
__global__ __launch_bounds__(256) void transpose_w_k(const float* __restrict__ w, _Float16* __restrict__ wT) {
    __shared__ float lds[32][33];
    int t = threadIdx.x;
    int col = t & 31;
    int rowg = t >> 5;
    int n0 = blockIdx.x * 32;
    int k0 = blockIdx.y * 32;
#pragma unroll
    for (int i = 0; i < 4; i++) {
        int r = rowg + i * 8;
        lds[r][col] = w[(size_t)(k0 + r) * NCOL + n0 + col];
    }
    __syncthreads();
#pragma unroll
    for (int i = 0; i < 4; i++) {
        int r = rowg + i * 8;
        int c = n0 + r;
        int row = (c % 5) * NOUT + (c / 5);
        wT[(size_t)row * NIN + k0 + col] = (_Float16)lds[col][r];
    }
}

// ---------------- Kernel 3: 8-phase 256x256 MFMA GEMM + fused gate epilogue ----------------
// A: xb [16384][1024] f16; BT: wT [2560][1024] f16 (gate-plane-permuted cols)
// Schedule (per K-tile = 4 phases, 16 MFMA each):
//   p1: ds_read all B-frags + A-sub0 | stage (t+1,A1) | bar | lgkm0 | MFMA Q(A0,B0) | bar
//   p2: ds_read A-sub1              | stage (t+2,B0) | bar | lgkm0 | MFMA Q(A1,B0) | bar
//   p3:                              | stage (t+2,B1) | bar |        MFMA Q(A1,B1) | bar
//   p4:                              | stage (t+2,A0) | bar |        MFMA Q(A0,B1) | vmcnt(6) | bar
// Staging writes only touch slots whose last ds_read completed >=1 phase earlier
// (B slots last read p1, A slots p2; issue phases p2/p3 and p4/p1' respectively).
// LDS swizzle: 16B-chunk k' = k ^ (row&7), applied to pre-swizzled GLOBAL source
// (global_load_lds dest stays linear, rule 21) and to ds_read addresses ->
// 8 lanes per 4-bank quad = conflict-free b128.
__global__ __launch_bounds__(512, 2) void gemm_gates_k(const _Float16* __restrict__ A,
                                                       const _Float16* __restrict__ BT,
                                                       const float* __restrict__ bias,
                                                       _Float16* __restrict__ planes) {
    __shared__ _Float16 lds[65536];  // 128 KiB: A slots [0,32768), B slots [32768,65536)
    const int t = threadIdx.x;
    const int w = t >> 6, lane = t & 63;
    const int q = lane >> 4, r16 = lane & 15;
    const int wm = (w >> 2) * 128;   // 0 / 128
    const int wn = (w & 3) * 64;     // 0 / 64 / 128 / 192
    const int ah = wm >> 7;          // which A half-slot this wave reads
    const int bh = wn >> 7;          // which B half-slot this wave reads
    const int wnl = wn & 127;        // row offset within B half-slot
    const int m0 = blockIdx.x * BM;
    const int n0 = blockIdx.y * BN;

    auto stage_obj = [&](int o) {
        if (o >= NOBJ) return;
        int tile = o >> 2, part = o & 3;     // parts: 0=B0 1=B1 2=A0 3=A1
        int d = tile & 1, h = part & 1;
        _Float16* slot = lds + ((part >= 2) ? 0 : 32768) + (d * 2 + h) * 8192;
        const _Float16* src = (part >= 2) ? (A + (size_t)(m0 + h * 128) * NIN)
                                          : (BT + (size_t)(n0 + h * 128) * NIN);
        int kb = tile * BK;
#pragma unroll
        for (int L = 0; L < 2; L++) {
            int c = t + L * 512;             // 16B chunk index in slot (linear dest)
            int r = c >> 3, kp = c & 7;
            int k = kp ^ (r & 7);            // inverse-swizzled source segment
            async16(src + (size_t)r * NIN + kb + k * 8, (char*)lds + ((char*)slot - (char*)lds) + c * 16);
        }
    };

    auto ldsrd = [&](const _Float16* slot, int row, int k) -> f16x8 {
        return *(const f16x8*)(slot + row * 64 + ((k ^ (row & 7)) << 3));
    };

    f32x4 acc[8][4] = {};
    f16x8 a0[4][2], a1[4][2], bfr[4][2];

    // Prologue: T0 fully + T1:{B0,B1,A0} in flight (7 objects, 14 loads)
    for (int o = 0; o < 7; o++) stage_obj(o);
    asm volatile("s_waitcnt vmcnt(6)" ::: "memory");   // T0's 8 loads complete
    __builtin_amdgcn_s_barrier();

#pragma unroll 2
    for (int tt = 0; tt < NTILES; tt++) {
        const int d = tt & 1;
        const _Float16* As = lds + (d * 2 + ah) * 8192;
        const _Float16* Bs = lds + 32768 + (d * 2 + bh) * 8192;
        const int ob = 4 * tt + 7;

        // ===== phase 1: all B-frags + A-sub0; MFMA Q(A0,B0) =====
#pragma unroll
        for (int j = 0; j < 4; j++)
#pragma unroll
            for (int h = 0; h < 2; h++)
                bfr[j][h] = ldsrd(Bs, wnl + j * 16 + r16, h * 4 + q);
#pragma unroll
        for (int i = 0; i < 4; i++)
#pragma unroll
            for (int h = 0; h < 2; h++)
                a0[i][h] = ldsrd(As, i * 16 + r16, h * 4 + q);
        stage_obj(ob);                        // (t+1, A1) -> dbuf d^1
        __builtin_amdgcn_s_barrier();
        asm volatile("s_waitcnt lgkmcnt(0)" ::: "memory");
        __builtin_amdgcn_sched_barrier(0);
        __builtin_amdgcn_s_setprio(1);
#pragma unroll
        for (int i = 0; i < 4; i++)
#pragma unroll
            for (int j = 0; j < 2; j++)
#pragma unroll
                for (int h = 0; h < 2; h++)
                    acc[i][j] = __builtin_amdgcn_mfma_f32_16x16x32_f16(a0[i][h], bfr[j][h], acc[i][j], 0, 0, 0);
        __builtin_amdgcn_s_setprio(0);
        __builtin_amdgcn_s_barrier();

        // ===== phase 2: A-sub1; MFMA Q(A1,B0) =====
#pragma unroll
        for (int i = 0; i < 4; i++)
#pragma unroll
            for (int h = 0; h < 2; h++)
                a1[i][h] = ldsrd(As, 64 + i * 16 + r16, h * 4 + q);
        stage_obj(ob + 1);                    // (t+2, B0) -> dbuf d (B reads done at p1)
        __builtin_amdgcn_s_barrier();
        asm volatile("s_waitcnt lgkmcnt(0)" ::: "memory");
        __builtin_amdgcn_sched_barrier(0);
        __builtin_amdgcn_s_setprio(1);
#pragma unroll
        for (int i = 0; i < 4; i++)
#pragma unroll
            for (int j = 0; j < 2; j++)
#pragma unroll
                for (int h = 0; h < 2; h++)
                    acc[4 + i][j] = __builtin_amdgcn_mfma_f32_16x16x32_f16(a1[i][h], bfr[j][h], acc[4 + i][j], 0, 0, 0);
        __builtin_amdgcn_s_setprio(0);
        __builtin_amdgcn_s_barrier();

        // ===== phase 3: MFMA Q(A1,B1) =====
        stage_obj(ob + 2);                    // (t+2, B1) -> dbuf d
        __builtin_amdgcn_s_barrier();
        __builtin_amdgcn_s_setprio(1);
#pragma unroll
        for (int i = 0; i < 4; i++)
#pragma unroll
            for (int j = 0; j < 2; j++)
#pragma unroll
                for (int h = 0; h < 2; h++)
                    acc[4 + i][2 + j] = __builtin_amdgcn_mfma_f32_16x16x32_f16(a1[i][h], bfr[2 + j][h], acc[4 + i][2 + j], 0, 0, 0);
        __builtin_amdgcn_s_setprio(0);
        __builtin_amdgcn_s_barrier();

        // ===== phase 4: MFMA Q(A0,B1); counted vmcnt =====
        stage_obj(ob + 3);                    // (t+2, A0) -> dbuf d (A reads done at p2)
        __builtin_amdgcn_s_barrier();
        __builtin_amdgcn_s_setprio(1);
#pragma unroll
        for (int i = 0; i < 4; i++)
#pragma unroll
            for (int j = 0; j < 2; j++)
#pragma unroll
                for (int h = 0; h < 2; h++)
                    acc[i][2 + j] = __builtin_amdgcn_mfma_f32_16x16x32_f16(a0[i][h], bfr[2 + j][h], acc[i][2 + j], 0, 0, 0);
        __builtin_amdgcn_s_setprio(0);
        if (tt < NTILES - 2) {
            asm volatile("s_waitcnt vmcnt(6)" ::: "memory");  // next tile complete, 3 HTs in flight
        } else {
            asm volatile("s_waitcnt vmcnt(0)" ::: "memory");  // tail drain
        }
        __builtin_amdgcn_s_barrier();
    }

    // Epilogue: fused gate nonlinearity, block-uniform gate (n0 multiple of 256, 256 | 512)
    int g = n0 >> 9;
    int nb = n0 & (NOUT - 1);
    _Float16* plane = planes + (size_t)g * PLANE;
#pragma unroll
    for (int j = 0; j < 4; j++) {
        int coln = nb + wn + j * 16 + r16;
        float bv = bias[n0 + wn + j * 16 + r16];
#pragma unroll
        for (int i = 0; i < 8; i++) {
#pragma unroll
            for (int reg = 0; reg < 4; reg++) {
                int m = m0 + wm + i * 16 + q * 4 + reg;
                float v = acc[i][j][reg];
                if (g >= 2) v = fsigmoid(v + bv);
                plane[(size_t)m * NOUT + coln] = (_Float16)v;
            }
        }
    }
}

// ---------------- Kernel 4a: compose per-segment affine maps (4 chains/thread, f16x4 loads) ----
// map: c' = A c + b, A=[[f1,0],[u2,f2]], b=[u1, eps*u2]
// SM planes: 0:a11 1:a21 2:a22 3:b1 4:b2, each [SEG][CHAINS] f32
__global__ __launch_bounds__(256) void compose_k(const _Float16* __restrict__ planes,
                                                 const float* __restrict__ beps,
                                                 float* __restrict__ SM) {
    int u = blockIdx.x * 256 + threadIdx.x;       // 0 .. SEG*CHAINS/4 - 1
    int t4 = u & (CHAINS / 4 - 1);
    int s = u >> 11;
    int tch = t4 << 2;
    int n = tch & (NOUT - 1);
    float eps[4], a11[4], a21[4], a22[4], b1[4], b2[4];
#pragma unroll
    for (int c = 0; c < 4; c++) {
        eps[c] = fsigmoid(beps[n + c]);
        a11[c] = 1.0f; a21[c] = 0.0f; a22[c] = 1.0f; b1[c] = 0.0f; b2[c] = 0.0f;
    }
    const f16x4* p4 = (const f16x4*)planes;
    const size_t P4 = PLANE >> 2;
#pragma unroll 4
    for (int j = 0; j < SLEN; j++) {
        size_t e = ((size_t)(s * SLEN + j) * CHAINS + tch) >> 2;
        f16x4 u1v = p4[e];
        f16x4 u2v = p4[P4 + e];
        f16x4 f1v = p4[2 * P4 + e];
        f16x4 f2v = p4[3 * P4 + e];
#pragma unroll
        for (int c = 0; c < 4; c++) {
            float u1 = (float)u1v[c], u2 = (float)u2v[c];
            float f1 = (float)f1v[c], f2 = (float)f2v[c];
            float na11 = f1 * a11[c];
            float na21 = fmaf(u2, a11[c], f2 * a21[c]);
            float na22 = f2 * a22[c];
            float nb1  = fmaf(f1, b1[c], u1);
            float nb2  = fmaf(u2, b1[c], fmaf(f2, b2[c], eps[c] * u2));
            a11[c] = na11; a21[c] = na21; a22[c] = na22; b1[c] = nb1; b2[c] = nb2;
        }
    }
    size_t idx = (size_t)s * CHAINS + tch;
    *(float4*)(SM + idx)           = make_float4(a11[0], a11[1], a11[2], a11[3]);
    *(float4*)(SM + SMP + idx)     = make_float4(a21[0], a21[1], a21[2], a21[3]);
    *(float4*)(SM + 2 * SMP + idx) = make_float4(a22[0], a22[1], a22[2], a22[3]);
    *(float4*)(SM + 3 * SMP + idx) = make_float4(b1[0], b1[1], b1[2], b1[3]);
    *(float4*)(SM + 4 * SMP + idx) = make_float4(b2[0], b2[1], b2[2], b2[3]);
}

// ---------------- Kernel 4b: sequential scan over segment maps ----------------
__global__ __launch_bounds__(256) void segscan_k(const float* __restrict__ SM,
                                                 float* __restrict__ segc,
                                                 float* __restrict__ out) {
    int t = blockIdx.x * 256 + threadIdx.x;  // 0..8191
    float c1 = 0.0f, c2 = 0.0f;
#pragma unroll
    for (int s = 0; s < SEG; s++) {
        size_t idx = (size_t)s * CHAINS + t;
        segc[idx] = c1;
        segc[SMP + idx] = c2;
        float a11 = SM[idx];
        float a21 = SM[SMP + idx];
        float a22 = SM[2 * SMP + idx];
        float b1  = SM[3 * SMP + idx];
        float b2  = SM[4 * SMP + idx];
        float c1n = fmaf(a11, c1, b1);
        float c2n = fmaf(a21, c1, fmaf(a22, c2, b2));
        c1 = c1n; c2 = c2n;
    }
    out[OUT_GCS + t] = c1;
    out[OUT_GCS + CHAINS + t] = c2;
}

// ---------------- Kernel 4c: apply within segments + fused output (4 chains/thread) ----------
__global__ __launch_bounds__(256) void apply_k(const _Float16* __restrict__ planes,
                                               const float* __restrict__ segc,
                                               const float* __restrict__ beps,
                                               const float* __restrict__ bfin,
                                               float* __restrict__ out) {
    int u = blockIdx.x * 256 + threadIdx.x;
    int t4 = u & (CHAINS / 4 - 1);
    int s = u >> 11;
    int tch = t4 << 2;
    int n = tch & (NOUT - 1);
    float eps[4], rho0[4], rho1[4], c1[4], c2[4];
#pragma unroll
    for (int c = 0; c < 4; c++) {
        eps[c]  = fsigmoid(beps[n + c]);
        rho0[c] = 2.0f * fsigmoid(bfin[2 * (n + c)]);
        rho1[c] = 2.0f * fsigmoid(bfin[2 * (n + c) + 1]);
    }
    size_t idx = (size_t)s * CHAINS + tch;
    float4 c1v = *(const float4*)(segc + idx);
    float4 c2v = *(const float4*)(segc + SMP + idx);
    c1[0] = c1v.x; c1[1] = c1v.y; c1[2] = c1v.z; c1[3] = c1v.w;
    c2[0] = c2v.x; c2[1] = c2v.y; c2[2] = c2v.z; c2[3] = c2v.w;
    const f16x4* p4 = (const f16x4*)planes;
    const size_t P4 = PLANE >> 2;
#pragma unroll 4
    for (int j = 0; j < SLEN; j++) {
        size_t e = (size_t)(s * SLEN + j) * CHAINS + tch;
        size_t e4 = e >> 2;
        f16x4 u1v = p4[e4];
        f16x4 u2v = p4[P4 + e4];
        f16x4 f1v = p4[2 * P4 + e4];
        f16x4 f2v = p4[3 * P4 + e4];
        f16x4 ov  = p4[4 * P4 + e4];
        float4 yv;
        float yr[4];
#pragma unroll
        for (int c = 0; c < 4; c++) {
            float u1 = (float)u1v[c], u2 = (float)u2v[c];
            float f1 = (float)f1v[c], f2 = (float)f2v[c];
            float o  = (float)ov[c];
            float c1p = c1[c];
            c1[c] = fmaf(c1p, f1, u1);
            c2[c] = fmaf(c2[c], f2, (eps[c] + c1p) * u2);
            float cs = fmaf(c1[c], rho0[c], c2[c] * rho1[c]);
            float y = o * cs;
            y = fminf(9.0f, fmaxf(-9.0f, y));
            float ex = __expf(2.0f * y);
            yr[c] = (ex - 1.0f) / (ex + 1.0f);   // tanh(y)
        }
        yv.x = yr[0]; yv.y = yr[1]; yv.z = yr[2]; yv.w = yr[3];
        *(float4*)(out + e) = yv;
    }
}

extern "C" void kernel_launch(void* const* d_in, const int* in_sizes, int n_in,
                              void* d_out, int out_size, void* d_ws, size_t ws_size,
                              hipStream_t stream) {
    const float* x    = (const float*)d_in[0];
    const float* wgt  = (const float*)d_in[1];
    const float* bias = (const float*)d_in[2];
    const float* beps = (const float*)d_in[3];
    const float* bfin = (const float*)d_in[4];
    float* out = (float*)d_out;

    // Workspace layout (~124 MB)
    char* p = (char*)d_ws;
    _Float16* wT     = (_Float16*)p; p += (size_t)NCOL * NIN * 2;        // 5 MB
    _Float16* xb     = (_Float16*)p; p += (size_t)MTOT * NIN * 2;        // 32 MB
    _Float16* planes = (_Float16*)p; p += 5 * PLANE * 2;                 // 80 MB
    float* SM        = (float*)p;    p += 5 * SMP * 4;                   // 5 MB
    float* segc      = (float*)p;    p += 2 * SMP * 4;                   // 2 MB

    transpose_w_k<<<dim3(NCOL / 32, NIN / 32), 256, 0, stream>>>(wgt, wT);

    int n8 = MTOT * NIN / 8;
    convert_x_k<<<dim3((n8 + 255) / 256), 256, 0, stream>>>(x, xb, n8);

    gemm_gates_k<<<dim3(MTOT / BM, NCOL / BN), 512, 0, stream>>>(xb, wT, bias, planes);

    compose_k<<<dim3(SEG * CHAINS / 4 / 256), 256, 0, stream>>>(planes, beps, SM);
    segscan_k<<<dim3(CHAINS / 256), 256, 0, stream>>>(SM, segc, out);
    apply_k<<<dim3(SEG * CHAINS / 4 / 256), 256, 0, stream>>>(planes, segc, beps, bfin, out);
}